// Round 4
// baseline (559.713 us; speedup 1.0000x reference)
//
#include <hip/hip_runtime.h>
#include <stdint.h>

// Problem constants
#define K_DIM   2048      // IN_DIM
#define NN      2047      // N_NODES
#define NPAD    2048      // padded node dim
#define BATCH   16384
#define ODIM    10
#define IOFF    (128 * 2048)   // +128 rows (A) / +128 cols (B) in elements

typedef __attribute__((ext_vector_type(8))) short  bf16x8;
typedef __attribute__((ext_vector_type(4))) float  f32x4;

static __device__ __forceinline__ unsigned short f2bf(float f) {
    union { float f; unsigned int u; } c; c.f = f;
    unsigned int u = c.u;
    return (unsigned short)((u + 0x7fffu + ((u >> 16) & 1u)) >> 16);
}
static __device__ __forceinline__ float bf2f(unsigned short h) {
    union { unsigned int u; float f; } c; c.u = ((unsigned int)h) << 16;
    return c.f;
}

// ---------------- fused fp32 -> bf16 conversion: in_x and padded W1 ----------------
__global__ __launch_bounds__(256) void cvt_all(const float* __restrict__ xs,
                                               const float* __restrict__ ws,
                                               unsigned short* __restrict__ dx,
                                               unsigned short* __restrict__ dw) {
    int b = blockIdx.x;
    union { unsigned short h[8]; uint4 v; } o;
    if (b < 16384) {
        int i = b * 256 + threadIdx.x;
        const float4* s = (const float4*)xs + (size_t)i * 2;
        float4 a = s[0], c = s[1];
        o.h[0] = f2bf(a.x); o.h[1] = f2bf(a.y); o.h[2] = f2bf(a.z); o.h[3] = f2bf(a.w);
        o.h[4] = f2bf(c.x); o.h[5] = f2bf(c.y); o.h[6] = f2bf(c.z); o.h[7] = f2bf(c.w);
        *((uint4*)dx + i) = o.v;
    } else {
        int i = (b - 16384) * 256 + threadIdx.x;
        size_t e = (size_t)i * 8;
        int row = (int)(e >> 11);
        if (row < NN) {
            const float4* s = (const float4*)(ws + e);
            float4 a = s[0], c = s[1];
            o.h[0] = f2bf(a.x); o.h[1] = f2bf(a.y); o.h[2] = f2bf(a.z); o.h[3] = f2bf(a.w);
            o.h[4] = f2bf(c.x); o.h[5] = f2bf(c.y); o.h[6] = f2bf(c.z); o.h[7] = f2bf(c.w);
        } else {
            o.v = make_uint4(0u, 0u, 0u, 0u);
        }
        *((uint4*)dw + i) = o.v;
    }
}

// ---------------- 256x256 bf16 MFMA GEMM, 4 waves, read-ahead pipeline ----------------
// A [16384][2048] bf16, B=W [2048][2048] bf16 (row 2047 zero), X = A@B^T + bias (bf16).
// 4 waves (2M x 2N), per-wave 128x128 output (acc 256 VGPR), 1 wave/SIMD (512-reg budget).
// Per tile: 4 windows [read next cluster frags][stage][MFMA x32][counted vmcnt][BAR].
__global__ __launch_bounds__(256, 1) void gemm4(const unsigned short* __restrict__ A,
                                                const unsigned short* __restrict__ B,
                                                const float* __restrict__ bias,
                                                unsigned short* __restrict__ X) {
    __shared__ char lds[131072];   // 2 buf x {A0,A1,B0,B1} x 16KiB

    const int t0   = threadIdx.x;
    const int w    = t0 >> 6;
    const int lane = t0 & 63;
    const int wm = w >> 1, wn = w & 1;     // wave -> 128x128 output block
    const int lr = lane & 15, lk = lane >> 4;
    const int xmask = (lr & 7) << 4;       // read-side swizzle

    // XCD-aware swizzle: 512 wgs, 64 per XCD
    int bid = blockIdx.x;
    int swz = (bid & 7) * 64 + (bid >> 3);
    const int rowBase = (swz >> 3) * 256;  // 64 row-tiles
    const int colBase = (swz & 7) * 256;   // 8 col-tiles

    // staging source pointers (pre-swizzled global addresses)
    const int li = lane >> 3;   // row-within-8
    const int lg = lane & 7;    // 16B granule
    const int rho = w * 8 + li; // 0..31
    const int gc  = (lg ^ li) * 8;
    const unsigned short* sA[2];
    const unsigned short* sB[2];
#pragma unroll
    for (int h = 0; h < 2; ++h) {
        sA[h] = A + (size_t)(rowBase + h * 64 + rho) * K_DIM + gc;
        sB[h] = B + (size_t)(colBase + h * 32 + rho) * K_DIM + gc;
    }

#define AS1 __attribute__((address_space(1)))
#define AS3 __attribute__((address_space(3)))
#define STAGE_(src, dstoff) \
    __builtin_amdgcn_global_load_lds((const AS1 void*)(src), \
        (AS3 void*)(lds + (dstoff) + w * 1024), 16, 0, 0)
#define STAGE_A4(hh, kt, p) do { const unsigned short* _s = sA[hh] + (kt) * 64; \
    const int _d = (p) * 65536 + (hh) * 16384; \
    STAGE_(_s, _d); STAGE_(_s + 32 * K_DIM, _d + 4096); \
    STAGE_(_s + IOFF, _d + 8192); STAGE_(_s + IOFF + 32 * K_DIM, _d + 12288); } while (0)
#define STAGE_B4(gg, kt, p) do { const unsigned short* _s = sB[gg] + (kt) * 64; \
    const int _d = (p) * 65536 + 32768 + (gg) * 16384; \
    STAGE_(_s, _d); STAGE_(_s + 64 * K_DIM, _d + 4096); \
    STAGE_(_s + IOFF, _d + 8192); STAGE_(_s + IOFF + 64 * K_DIM, _d + 12288); } while (0)

#define LDSA(bo, hh, mq, ks) (*(const bf16x8*)(lds + (bo) + (hh) * 16384 + \
        (wm * 64 + (mq) * 16 + lr) * 128 + (((ks) * 64 + lk * 16) ^ xmask)))
#define LDSB(bo, gg, hb, nn, ks) (*(const bf16x8*)(lds + (bo) + 32768 + (gg) * 16384 + \
        (wn * 64 + (hb) * 32 + (nn) * 16 + lr) * 128 + (((ks) * 64 + lk * 16) ^ xmask)))

#define BAR()   __builtin_amdgcn_s_barrier()
#define VM12()  asm volatile("s_waitcnt vmcnt(12)" ::: "memory")
#define VM16()  asm volatile("s_waitcnt vmcnt(16)" ::: "memory")
#define PRIO1() __builtin_amdgcn_s_setprio(1)
#define PRIO0() __builtin_amdgcn_s_setprio(0)

    f32x4 acc[8][8];
#pragma unroll
    for (int m = 0; m < 8; ++m)
#pragma unroll
        for (int n = 0; n < 8; ++n) acc[m][n] = (f32x4)0.f;

    bf16x8 aF0[4][2], aF1[4][2], bH1[4][2], bH0a[4][2], bH0b[4][2];

#define RD_A(dst, bo, hh) do { \
    _Pragma("unroll") for (int mq = 0; mq < 4; ++mq) \
    _Pragma("unroll") for (int ks = 0; ks < 2; ++ks) dst[mq][ks] = LDSA(bo, hh, mq, ks); } while (0)
#define RD_B(dst, bo, hb) do { \
    _Pragma("unroll") for (int g = 0; g < 2; ++g) \
    _Pragma("unroll") for (int nn = 0; nn < 2; ++nn) \
    _Pragma("unroll") for (int ks = 0; ks < 2; ++ks) dst[g * 2 + nn][ks] = LDSB(bo, g, hb, nn, ks); } while (0)

#define CL(MB, NB, AF, BF) do { \
    _Pragma("unroll") for (int mq = 0; mq < 4; ++mq) \
    _Pragma("unroll") for (int q = 0; q < 4; ++q) \
    _Pragma("unroll") for (int ks = 0; ks < 2; ++ks) \
        acc[(MB) + mq][(NB) + q] = __builtin_amdgcn_mfma_f32_16x16x32_bf16( \
            AF[mq][ks], BF[q][ks], acc[(MB) + mq][(NB) + q], 0, 0, 0); } while (0)

    // ---- prologue: tile0 full (16 loads) + tile1 {A0,B0,B1} (12 loads) ----
    STAGE_A4(0, 0, 0); STAGE_A4(1, 0, 0); STAGE_B4(0, 0, 0); STAGE_B4(1, 0, 0);
    STAGE_A4(0, 1, 1); STAGE_B4(0, 1, 1); STAGE_B4(1, 1, 1);
    VM12(); BAR();
    RD_A(aF0, 0, 0);     // A0(0)
    RD_B(bH0a, 0, 0);    // Bh0(0)

    // Per tile: stage schedule C1:A1(T+1)->bp, C2:A0(T+2)->bo, C3:B0(T+2)->bo, C4:B1(T+2)->bo.
    // Guards: C1-end VM16 (A1(T) for W2), C2-end VM16 (A0(T+1) for W3),
    //         C3-end VM12 (B1(T+1) for W4's Bh0 read spanning both B regions),
    //         C4-end VM16 (B1(T+1)... for next-tile W1's Bh1 read).
#define TILE(T, PAR, CUR, NXT) do { \
    const int _bo = (PAR) * 65536, _bp = ((PAR) ^ 1) * 65536; \
    const int _k1 = ((T) + 1) & 31, _k2 = ((T) + 2) & 31; \
    /* W1: read Bh1(T); stage A1(T+1); C1 = A0 x Bh0 */ \
    RD_B(bH1, _bo, 1); STAGE_A4(1, _k1, (PAR) ^ 1); \
    PRIO1(); CL(0, 0, aF0, CUR); PRIO0(); VM16(); BAR(); \
    /* W2: read A1(T); stage A0(T+2); C2 = A0 x Bh1 */ \
    RD_A(aF1, _bo, 1); STAGE_A4(0, _k2, (PAR)); \
    PRIO1(); CL(0, 4, aF0, bH1); PRIO0(); VM16(); BAR(); \
    /* W3: read A0(T+1) from bp; stage B0(T+2); C3 = A1 x Bh1 */ \
    RD_A(aF0, _bp, 0); STAGE_B4(0, _k2, (PAR)); \
    PRIO1(); CL(4, 4, aF1, bH1); PRIO0(); VM12(); BAR(); \
    /* W4: read Bh0(T+1) from bp; stage B1(T+2); C4 = A1 x Bh0 */ \
    RD_B(NXT, _bp, 0); STAGE_B4(1, _k2, (PAR)); \
    PRIO1(); CL(4, 0, aF1, CUR); PRIO0(); VM16(); BAR(); \
} while (0)

    for (int tp = 0; tp < 16; ++tp) {
        TILE(tp * 2,     0, bH0a, bH0b);
        TILE(tp * 2 + 1, 1, bH0b, bH0a);
    }

    // ---- epilogue: + bias, store bf16 ----
    float bb[8];
#pragma unroll
    for (int n = 0; n < 8; ++n) {
        int col = colBase + wn * 128 + (n >> 2) * 64 + ((n >> 1) & 1) * 32 + (n & 1) * 16 + lr;
        bb[n] = (col < NN) ? bias[col] : 0.f;
    }
#pragma unroll
    for (int mi = 0; mi < 8; ++mi) {
        int row = rowBase + wm * 128 + (mi >> 2) * 64 + (mi & 3) * 16 + lk * 4;
#pragma unroll
        for (int j = 0; j < 4; ++j) {
            unsigned short* xr = X + (size_t)(row + j) * NPAD + colBase + wn * 128;
#pragma unroll
            for (int n = 0; n < 8; ++n)
                xr[(n >> 2) * 64 + ((n >> 1) & 1) * 32 + (n & 1) * 16 + lr] = f2bf(acc[mi][n][j] + bb[n]);
        }
    }
}

// ---------------- tree kernel: out[b,a] = S_abs[b] - min_{leaf≡a mod 10} pathPenalty ----------------
__global__ __launch_bounds__(256) void tree_kernel(const unsigned short* __restrict__ X,
                                                   float* __restrict__ out) {
    __shared__ float xs[4][2048];
    __shared__ float cm[4][64][ODIM];
    const int w    = threadIdx.x >> 6;
    const int lane = threadIdx.x & 63;
    const int row  = blockIdx.x * 4 + w;
    const unsigned short* xr = X + (size_t)row * NPAD;

#pragma unroll
    for (int i = 0; i < 4; ++i) {
        int base = i * 512 + lane * 8;
        uint4 v = *(const uint4*)(xr + base);
        const unsigned short* h = (const unsigned short*)&v;
#pragma unroll
        for (int j = 0; j < 8; ++j) xs[w][base + j] = bf2f(h[j]);
    }
    __syncthreads();

    float sabs = 0.f;
#pragma unroll
    for (int i = 0; i < 32; ++i) sabs += fabsf(xs[w][lane + i * 64]);
#pragma unroll
    for (int d = 1; d < 64; d <<= 1) sabs += __shfl_xor(sabs, d, 64);

    const int L = lane;
    float bp = 0.f;
#pragma unroll
    for (int l = 0; l <= 5; ++l) {
        float v = xs[w][(1 << l) - 1 + (L >> (6 - l))];
        bp += ((L >> (5 - l)) & 1) ? fmaxf(v, 0.f) : fmaxf(-v, 0.f);
    }
    float p2[2], p4[4], p8[8], p16[16], p32[32];
    {
        float v = xs[w][63 + L];
        p2[0] = bp + fmaxf(-v, 0.f);
        p2[1] = bp + fmaxf(v, 0.f);
    }
#pragma unroll
    for (int c = 0; c < 2; ++c) {
        float v = xs[w][127 + 2 * L + c];
        p4[2 * c]     = p2[c] + fmaxf(-v, 0.f);
        p4[2 * c + 1] = p2[c] + fmaxf(v, 0.f);
    }
#pragma unroll
    for (int c = 0; c < 4; ++c) {
        float v = xs[w][255 + 4 * L + c];
        p8[2 * c]     = p4[c] + fmaxf(-v, 0.f);
        p8[2 * c + 1] = p4[c] + fmaxf(v, 0.f);
    }
#pragma unroll
    for (int c = 0; c < 8; ++c) {
        float v = xs[w][511 + 8 * L + c];
        p16[2 * c]     = p8[c] + fmaxf(-v, 0.f);
        p16[2 * c + 1] = p8[c] + fmaxf(v, 0.f);
    }
#pragma unroll
    for (int c = 0; c < 16; ++c) {
        float v = xs[w][1023 + 16 * L + c];
        p32[2 * c]     = p16[c] + fmaxf(-v, 0.f);
        p32[2 * c + 1] = p16[c] + fmaxf(v, 0.f);
    }

    float m[ODIM];
#pragma unroll
    for (int r = 0; r < ODIM; ++r) m[r] = 1e30f;
#pragma unroll
    for (int tt = 0; tt < 32; ++tt) m[tt % ODIM] = fminf(m[tt % ODIM], p32[tt]);

    int base_mod = (L * 32) % ODIM;
#pragma unroll
    for (int r = 0; r < ODIM; ++r) {
        int a = base_mod + r; if (a >= ODIM) a -= ODIM;
        cm[w][L][a] = m[r];
    }
    __syncthreads();

    if (lane < ODIM) {
        float mn = 1e30f;
        for (int l2 = 0; l2 < 64; ++l2) mn = fminf(mn, cm[w][l2][lane]);
        out[(size_t)row * ODIM + lane] = sabs - mn;
    }
}

extern "C" void kernel_launch(void* const* d_in, const int* in_sizes, int n_in,
                              void* d_out, int out_size, void* d_ws, size_t ws_size,
                              hipStream_t stream) {
    const float* in_x = (const float*)d_in[0];
    const float* W1   = (const float*)d_in[1];
    const float* b1   = (const float*)d_in[2];

    unsigned short* Abf = (unsigned short*)d_ws;                      // 16384*2048 bf16
    unsigned short* Wbf = Abf + (size_t)BATCH * K_DIM;                // 2048*2048 bf16
    unsigned short* Xbf = Wbf + (size_t)NPAD * K_DIM;                 // 16384*2048 bf16
    float* out = (float*)d_out;

    cvt_all<<<18432, 256, 0, stream>>>(in_x, W1, Abf, Wbf);
    gemm4<<<512, 256, 0, stream>>>(Abf, Wbf, b1, Xbf);
    tree_kernel<<<BATCH / 4, 256, 0, stream>>>(Xbf, out);
}

// Round 5
// 194.386 us; speedup vs baseline: 2.8794x; 2.8794x over previous
//
#include <hip/hip_runtime.h>
#include <stdint.h>

// Problem constants
#define K_DIM   2048      // IN_DIM
#define NN      2047      // N_NODES
#define NPAD    2048      // padded node dim
#define BATCH   16384
#define ODIM    10
#define IOFF    (128 * 2048)   // +128 rows (A) / +128 cols (B) in elements

typedef __attribute__((ext_vector_type(8))) short   bf16x8;
typedef __attribute__((ext_vector_type(16))) float  f32x16;

static __device__ __forceinline__ unsigned short f2bf(float f) {
    union { float f; unsigned int u; } c; c.f = f;
    unsigned int u = c.u;
    return (unsigned short)((u + 0x7fffu + ((u >> 16) & 1u)) >> 16);
}
static __device__ __forceinline__ float bf2f(unsigned short h) {
    union { unsigned int u; float f; } c; c.u = ((unsigned int)h) << 16;
    return c.f;
}

// ---------------- fused fp32 -> bf16 conversion: in_x and padded W1 ----------------
__global__ __launch_bounds__(256) void cvt_all(const float* __restrict__ xs,
                                               const float* __restrict__ ws,
                                               unsigned short* __restrict__ dx,
                                               unsigned short* __restrict__ dw) {
    int b = blockIdx.x;
    union { unsigned short h[8]; uint4 v; } o;
    if (b < 16384) {
        int i = b * 256 + threadIdx.x;
        const float4* s = (const float4*)xs + (size_t)i * 2;
        float4 a = s[0], c = s[1];
        o.h[0] = f2bf(a.x); o.h[1] = f2bf(a.y); o.h[2] = f2bf(a.z); o.h[3] = f2bf(a.w);
        o.h[4] = f2bf(c.x); o.h[5] = f2bf(c.y); o.h[6] = f2bf(c.z); o.h[7] = f2bf(c.w);
        *((uint4*)dx + i) = o.v;
    } else {
        int i = (b - 16384) * 256 + threadIdx.x;
        size_t e = (size_t)i * 8;
        int row = (int)(e >> 11);
        if (row < NN) {
            const float4* s = (const float4*)(ws + e);
            float4 a = s[0], c = s[1];
            o.h[0] = f2bf(a.x); o.h[1] = f2bf(a.y); o.h[2] = f2bf(a.z); o.h[3] = f2bf(a.w);
            o.h[4] = f2bf(c.x); o.h[5] = f2bf(c.y); o.h[6] = f2bf(c.z); o.h[7] = f2bf(c.w);
        } else {
            o.v = make_uint4(0u, 0u, 0u, 0u);
        }
        *((uint4*)dw + i) = o.v;
    }
}

// ---------------- 256x256 bf16 GEMM, 8 waves, 32x32x16 MFMA, 1-barrier phases ----------------
// X = A @ W^T + bias. Staging layout/pointers identical to R3 (proven).
// Per tile: 4 phases, each [ds_reads | stage | sched_barrier | MFMA x8 (32x32x16) | VM | BAR].
// B fragments read ahead (2 rotating sets); A fragments lockstep (single set).
__global__ __launch_bounds__(512, 1) void gemm32(const unsigned short* __restrict__ A,
                                                 const unsigned short* __restrict__ B,
                                                 const float* __restrict__ bias,
                                                 unsigned short* __restrict__ X) {
    __shared__ char lds[131072];   // 2 buf x {A0,A1,B0,B1} x 16KiB

    const int t0   = threadIdx.x;
    const int w    = t0 >> 6;
    const int lane = t0 & 63;
    const int wm = w >> 2, wn = w & 3;     // wave -> 128 rows x 64 cols
    const int lr5 = lane & 31, hi5 = lane >> 5;
    const int xm5 = (lr5 & 7) << 4;        // read-side swizzle

    // XCD-aware swizzle: 512 wgs, 64 per XCD
    int bid = blockIdx.x;
    int swz = (bid & 7) * 64 + (bid >> 3);
    const int rowBase = (swz >> 3) * 256;  // 64 row-tiles
    const int colBase = (swz & 7) * 256;   // 8 col-tiles

    // staging source pointers (pre-swizzled global addresses) — R3 verbatim
    const int li = lane >> 3;   // row-within-8
    const int lg = lane & 7;    // 16B granule
    const unsigned short* sA[2];
    const unsigned short* sB[2];
    {
        int rho = w * 8 + li;                              // 0..63
        int gc  = (lg ^ (rho & 7)) * 8;                    // swizzled k-granule
#pragma unroll
        for (int h = 0; h < 2; ++h) {
            sA[h] = A + (size_t)(rowBase + h * 64 + rho) * K_DIM + gc;
            sB[h] = B + (size_t)(colBase + (rho >> 5) * 64 + h * 32 + (rho & 31)) * K_DIM + gc;
        }
    }

#define AS1 __attribute__((address_space(1)))
#define AS3 __attribute__((address_space(3)))
#define STAGE_(src, dstoff) \
    __builtin_amdgcn_global_load_lds((const AS1 void*)(src), \
        (AS3 void*)(lds + (dstoff) + w * 1024), 16, 0, 0)
#define STAGE_A(hh, kt, p) do { const unsigned short* _s = sA[hh] + (kt) * 64; \
    const int _d = (p) * 65536 + (hh) * 16384; \
    STAGE_(_s, _d); STAGE_(_s + IOFF, _d + 8192); } while (0)
#define STAGE_B(gg, kt, p) do { const unsigned short* _s = sB[gg] + (kt) * 64; \
    const int _d = (p) * 65536 + 32768 + (gg) * 16384; \
    STAGE_(_s, _d); STAGE_(_s + IOFF, _d + 8192); } while (0)

    // 32x32x16 fragment reads. A: row = wm*128 + half*64 + mb*32 + lr5, k-slice ks.
#define LDSA32(bo, half, mb, ks) (*(const bf16x8*)(lds + (bo) + (half) * 16384 + wm * 8192 + \
        ((mb) * 32 + lr5) * 128 + (((ks) * 32 + hi5 * 16) ^ xm5)))
    // B: col = wn*64 + hb*32 + lr5 -> region hb, part wn>>1, local row (wn&1)*32+lr5.
#define LDSB32(bo, hb, ks) (*(const bf16x8*)(lds + (bo) + 32768 + (hb) * 16384 + (wn >> 1) * 8192 + \
        ((wn & 1) * 32 + lr5) * 128 + (((ks) * 32 + hi5 * 16) ^ xm5)))

#define BAR()   __builtin_amdgcn_s_barrier()
#define SB0()   __builtin_amdgcn_sched_barrier(0)
#define VM6()   asm volatile("s_waitcnt vmcnt(6)" ::: "memory")
#define VM8()   asm volatile("s_waitcnt vmcnt(8)" ::: "memory")
#define VM10()  asm volatile("s_waitcnt vmcnt(10)" ::: "memory")
#define PRIO1() __builtin_amdgcn_s_setprio(1)
#define PRIO0() __builtin_amdgcn_s_setprio(0)

    f32x16 acc[2][2][2];   // [half][mb][hb]
#pragma unroll
    for (int h = 0; h < 2; ++h)
#pragma unroll
        for (int m = 0; m < 2; ++m)
#pragma unroll
            for (int n = 0; n < 2; ++n) acc[h][m][n] = (f32x16)0.f;

    bf16x8 aF[2][4];       // A fragments of current half: [mb][ks]
    bf16x8 bX[4], bY[4];   // two rotating B sets: [ks]

#define RD_A32(bo, half) do { \
    _Pragma("unroll") for (int mb = 0; mb < 2; ++mb) \
    _Pragma("unroll") for (int ks = 0; ks < 4; ++ks) aF[mb][ks] = LDSA32(bo, half, mb, ks); } while (0)
#define RD_B32(dst, bo, hb) do { \
    _Pragma("unroll") for (int ks = 0; ks < 4; ++ks) dst[ks] = LDSB32(bo, hb, ks); } while (0)

#define CL32(HALF, HB, BF) do { \
    _Pragma("unroll") for (int mb = 0; mb < 2; ++mb) \
    _Pragma("unroll") for (int ks = 0; ks < 4; ++ks) \
        acc[HALF][mb][HB] = __builtin_amdgcn_mfma_f32_32x32x16_bf16( \
            aF[mb][ks], BF[ks], acc[HALF][mb][HB], 0, 0, 0); } while (0)

    // ---- prologue: tile0 {A0,A1,B0,B1}, tile1 {A0,B0,B1}; VM6 guards B1(0) ----
    STAGE_A(0, 0, 0); STAGE_A(1, 0, 0); STAGE_B(0, 0, 0); STAGE_B(1, 0, 0);
    STAGE_A(0, 1, 1); STAGE_B(0, 1, 1); STAGE_B(1, 1, 1);
    VM6(); BAR();
    RD_B32(bX, 0, 0);      // cur0(tile0) = B0(0)

    // Per tile T (BC0 = cur0 set, BC1 = cur1 set):
    //  W1: read A0(T)+B1(T->BC1); stage A1(T+1);          MFMA C1 = A0 x BC0
    //  W2: (no reads);            stage A0(T+2);          MFMA C2 = A0 x BC1   [VM10]
    //  W3: read A1(T);            stage B0(T+2);          MFMA C3 = A1 x BC1   [VM8]
    //  W4: read B0(T+1)->BC1;     stage B1(T+2);          MFMA C4 = A1 x BC0   [VM8]
    // Next tile: BC0' = BC1 (holds B0(T+1)), BC1' = BC0 (dead).
#define TILE32(T, PAR, BC0, BC1) do { \
    const int _bo = (PAR) * 65536, _bp = ((PAR) ^ 1) * 65536; \
    const int _k1 = ((T) + 1) & 31, _k2 = ((T) + 2) & 31; \
    RD_A32(_bo, 0); RD_B32(BC1, _bo, 1); STAGE_A(1, _k1, (PAR) ^ 1); \
    SB0(); PRIO1(); CL32(0, 0, BC0); PRIO0(); BAR(); \
    STAGE_A(0, _k2, (PAR)); \
    SB0(); PRIO1(); CL32(0, 1, BC1); PRIO0(); VM10(); BAR(); \
    RD_A32(_bo, 1); STAGE_B(0, _k2, (PAR)); \
    SB0(); PRIO1(); CL32(1, 1, BC1); PRIO0(); VM8(); BAR(); \
    RD_B32(BC1, _bp, 0); STAGE_B(1, _k2, (PAR)); \
    SB0(); PRIO1(); CL32(1, 0, BC0); PRIO0(); VM8(); BAR(); \
} while (0)

    for (int tp = 0; tp < 16; ++tp) {
        TILE32(tp * 2,     0, bX, bY);
        TILE32(tp * 2 + 1, 1, bY, bX);
    }

    // ---- epilogue: + bias, store bf16. C/D: col=lane&31, row=(reg&3)+8*(reg>>2)+4*hi5 ----
    float bb[2];
#pragma unroll
    for (int hb = 0; hb < 2; ++hb) {
        int col = colBase + wn * 64 + hb * 32 + lr5;
        bb[hb] = (col < NN) ? bias[col] : 0.f;
    }
#pragma unroll
    for (int half = 0; half < 2; ++half)
#pragma unroll
        for (int mb = 0; mb < 2; ++mb)
#pragma unroll
            for (int hb = 0; hb < 2; ++hb) {
                int colb = colBase + wn * 64 + hb * 32 + lr5;
#pragma unroll
                for (int reg = 0; reg < 16; ++reg) {
                    int roff = (reg & 3) + 8 * (reg >> 2) + 4 * hi5;
                    int row = rowBase + wm * 128 + half * 64 + mb * 32 + roff;
                    X[(size_t)row * NPAD + colb] = f2bf(acc[half][mb][hb][reg] + bb[hb]);
                }
            }
}

// ---------------- tree kernel: out[b,a] = S_abs[b] - min_{leaf≡a mod 10} pathPenalty ----------------
__global__ __launch_bounds__(256) void tree_kernel(const unsigned short* __restrict__ X,
                                                   float* __restrict__ out) {
    __shared__ float xs[4][2048];
    __shared__ float cm[4][64][ODIM];
    const int w    = threadIdx.x >> 6;
    const int lane = threadIdx.x & 63;
    const int row  = blockIdx.x * 4 + w;
    const unsigned short* xr = X + (size_t)row * NPAD;

#pragma unroll
    for (int i = 0; i < 4; ++i) {
        int base = i * 512 + lane * 8;
        uint4 v = *(const uint4*)(xr + base);
        const unsigned short* h = (const unsigned short*)&v;
#pragma unroll
        for (int j = 0; j < 8; ++j) xs[w][base + j] = bf2f(h[j]);
    }
    __syncthreads();

    float sabs = 0.f;
#pragma unroll
    for (int i = 0; i < 32; ++i) sabs += fabsf(xs[w][lane + i * 64]);
#pragma unroll
    for (int d = 1; d < 64; d <<= 1) sabs += __shfl_xor(sabs, d, 64);

    const int L = lane;
    float bp = 0.f;
#pragma unroll
    for (int l = 0; l <= 5; ++l) {
        float v = xs[w][(1 << l) - 1 + (L >> (6 - l))];
        bp += ((L >> (5 - l)) & 1) ? fmaxf(v, 0.f) : fmaxf(-v, 0.f);
    }
    float p2[2], p4[4], p8[8], p16[16], p32[32];
    {
        float v = xs[w][63 + L];
        p2[0] = bp + fmaxf(-v, 0.f);
        p2[1] = bp + fmaxf(v, 0.f);
    }
#pragma unroll
    for (int c = 0; c < 2; ++c) {
        float v = xs[w][127 + 2 * L + c];
        p4[2 * c]     = p2[c] + fmaxf(-v, 0.f);
        p4[2 * c + 1] = p2[c] + fmaxf(v, 0.f);
    }
#pragma unroll
    for (int c = 0; c < 4; ++c) {
        float v = xs[w][255 + 4 * L + c];
        p8[2 * c]     = p4[c] + fmaxf(-v, 0.f);
        p8[2 * c + 1] = p4[c] + fmaxf(v, 0.f);
    }
#pragma unroll
    for (int c = 0; c < 8; ++c) {
        float v = xs[w][511 + 8 * L + c];
        p16[2 * c]     = p8[c] + fmaxf(-v, 0.f);
        p16[2 * c + 1] = p8[c] + fmaxf(v, 0.f);
    }
#pragma unroll
    for (int c = 0; c < 16; ++c) {
        float v = xs[w][1023 + 16 * L + c];
        p32[2 * c]     = p16[c] + fmaxf(-v, 0.f);
        p32[2 * c + 1] = p16[c] + fmaxf(v, 0.f);
    }

    float m[ODIM];
#pragma unroll
    for (int r = 0; r < ODIM; ++r) m[r] = 1e30f;
#pragma unroll
    for (int tt = 0; tt < 32; ++tt) m[tt % ODIM] = fminf(m[tt % ODIM], p32[tt]);

    int base_mod = (L * 32) % ODIM;
#pragma unroll
    for (int r = 0; r < ODIM; ++r) {
        int a = base_mod + r; if (a >= ODIM) a -= ODIM;
        cm[w][L][a] = m[r];
    }
    __syncthreads();

    if (lane < ODIM) {
        float mn = 1e30f;
        for (int l2 = 0; l2 < 64; ++l2) mn = fminf(mn, cm[w][l2][lane]);
        out[(size_t)row * ODIM + lane] = sabs - mn;
    }
}

extern "C" void kernel_launch(void* const* d_in, const int* in_sizes, int n_in,
                              void* d_out, int out_size, void* d_ws, size_t ws_size,
                              hipStream_t stream) {
    const float* in_x = (const float*)d_in[0];
    const float* W1   = (const float*)d_in[1];
    const float* b1   = (const float*)d_in[2];

    unsigned short* Abf = (unsigned short*)d_ws;                      // 16384*2048 bf16
    unsigned short* Wbf = Abf + (size_t)BATCH * K_DIM;                // 2048*2048 bf16
    unsigned short* Xbf = Wbf + (size_t)NPAD * K_DIM;                 // 16384*2048 bf16
    float* out = (float*)d_out;

    cvt_all<<<18432, 256, 0, stream>>>(in_x, W1, Abf, Wbf);
    gemm32<<<512, 512, 0, stream>>>(Abf, Wbf, b1, Xbf);
    tree_kernel<<<BATCH / 4, 256, 0, stream>>>(Xbf, out);
}